// Round 3
// baseline (410.564 us; speedup 1.0000x reference)
//
#include <hip/hip_runtime.h>
#include <hip/hip_bf16.h>

typedef __bf16 bf16x8 __attribute__((ext_vector_type(8)));
typedef float  f32x4  __attribute__((ext_vector_type(4)));

#define Bsz 64
#define Tdim 2048
#define Edim 512
#define Ddim 1024
#define Udim 128
#define NCHUNK 32          // Tdim / 64

__device__ inline unsigned short f2bf(float f) {
    union { float f; unsigned int u; } x{f};
    unsigned int r = x.u + 0x7FFFu + ((x.u >> 16) & 1u);   // RNE
    return (unsigned short)(r >> 16);
}

__device__ inline float fast_tanh(float x) {
    float e = __expf(2.f * x);                 // inf for large x -> returns 1; 0 for very neg -> -1
    return 1.f - __fdividef(2.f, e + 1.f);
}

// ---- K_prep: multi-role. blocks [0,2048): qb[b,u]; [2048,2112): Wk->bf16; block 2048 zeroes cnt ----
__global__ __launch_bounds__(256) void k_prep(const float* __restrict__ q,
                                              const float* __restrict__ Wq,
                                              const float* __restrict__ bparam,
                                              const float* __restrict__ convb,
                                              const float* __restrict__ Wk,
                                              unsigned short* __restrict__ wkbf,
                                              float* __restrict__ qb,
                                              int* __restrict__ cnt) {
    int bid = blockIdx.x, tid = threadIdx.x;
    if (bid >= 2048) {
        int cb = bid - 2048;
        if (cb == 0 && tid < Bsz) cnt[tid] = 0;
        int i = (cb * 256 + tid) * 4;
        float4 v = *reinterpret_cast<const float4*>(Wk + i);
        ushort4 h = make_ushort4(f2bf(v.x), f2bf(v.y), f2bf(v.z), f2bf(v.w));
        *reinterpret_cast<ushort4*>(wkbf + i) = h;
        return;
    }
    int gw   = bid * 4 + (tid >> 6);
    int lane = tid & 63;
    int b = gw >> 7, u = gw & 127;
    const float* qr = q  + (size_t)b * Ddim;
    const float* wr = Wq + (size_t)u * Ddim;
    float s = 0.f;
    #pragma unroll
    for (int i = 0; i < 4; ++i) {
        int base = lane * 16 + i * 4;
        float4 a = *reinterpret_cast<const float4*>(qr + base);
        float4 w = *reinterpret_cast<const float4*>(wr + base);
        s += a.x * w.x + a.y * w.y + a.z * w.z + a.w * w.w;
    }
    #pragma unroll
    for (int m = 32; m; m >>= 1) s += __shfl_xor(s, m);
    if (lane == 0) qb[gw] = s + bparam[u] + convb[u];
}

// ---- K1: fused score + partial softmax + partial context + last-block combine ----
__global__ __launch_bounds__(256) void k_score_ctx(const float* __restrict__ enc,
                                                   const float* __restrict__ prev,
                                                   const unsigned short* __restrict__ wkbf,
                                                   const float* __restrict__ qb,
                                                   const float* __restrict__ conv_w,
                                                   const float* __restrict__ v_w,
                                                   const float* __restrict__ v_b,
                                                   const int* __restrict__ lengths,
                                                   float* __restrict__ attn,
                                                   float* __restrict__ m_ws,
                                                   float* __restrict__ l_ws,
                                                   float* __restrict__ c_ws,
                                                   float* __restrict__ ctx,
                                                   int* __restrict__ cnt) {
    __shared__ alignas(16) unsigned short At[64 * 64];      // 8 KB, swizzled
    __shared__ alignas(16) unsigned short Bt[128 * 64];     // 16 KB, swizzled
    __shared__ float s_prev[66];
    __shared__ float s_qb[128];
    __shared__ float s_vw[128];
    __shared__ float s_cw[3][128];
    __shared__ float s_score[64];
    __shared__ float s_p[64];
    __shared__ alignas(16) float s_cred[128 * 4];           // 2 KB reduce buffer
    __shared__ float s_w[NCHUNK];
    __shared__ float sM, sinvL;
    __shared__ int   s_ret;

    const int tid   = threadIdx.x;
    const int b     = blockIdx.y;
    const int chunk = blockIdx.x;
    const int t0    = chunk * 64;
    const int lane  = tid & 63, wid = tid >> 6;
    const int len   = lengths[b];
    const int pidx  = b * NCHUNK + chunk;
    const bool active = (t0 < len);

    if (active) {
        if (tid < 128) {
            s_qb[tid]    = qb[b * 128 + tid];
            s_vw[tid]    = v_w[tid];
            s_cw[0][tid] = conv_w[tid * 3 + 0];
            s_cw[1][tid] = conv_w[tid * 3 + 1];
            s_cw[2][tid] = conv_w[tid * 3 + 2];
        }
        if (tid < 66) {
            int idx = t0 - 1 + tid;
            s_prev[tid] = (idx >= 0 && idx < Tdim) ? prev[b * Tdim + idx] : 0.f;
        }

        const float* encb = enc + ((size_t)b * Tdim + t0) * Edim;

        // hoisted per-thread bases for staging (T14 reg-staged pipeline)
        const float* pa[4]; const unsigned short* pb[4];
        int offA[4], offB[4];
        #pragma unroll
        for (int i = 0; i < 4; ++i) {
            int lin = tid + i * 256;
            int r = lin >> 4, c4 = lin & 15;
            pa[i]   = encb + (size_t)r * Edim + c4 * 4;
            offA[i] = (r * 128 + c4 * 8) ^ ((r & 7) << 4);
            int u = lin >> 3, c8 = lin & 7;
            pb[i]   = wkbf + (size_t)u * Edim + c8 * 8;
            offB[i] = (u * 128 + c8 * 16) ^ ((u & 7) << 4);
        }

        f32x4 acc[8];
        #pragma unroll
        for (int n = 0; n < 8; ++n) acc[n] = (f32x4){0.f, 0.f, 0.f, 0.f};

        float4 ra[4]; uint4 rb[4];
        #pragma unroll
        for (int i = 0; i < 4; ++i) {
            ra[i] = *reinterpret_cast<const float4*>(pa[i]);
            rb[i] = *reinterpret_cast<const uint4*>(pb[i]);
        }

        for (int e0 = 0; e0 < Edim; e0 += 64) {
            // consume current regs -> LDS
            #pragma unroll
            for (int i = 0; i < 4; ++i) {
                ushort4 h = make_ushort4(f2bf(ra[i].x), f2bf(ra[i].y), f2bf(ra[i].z), f2bf(ra[i].w));
                *reinterpret_cast<ushort4*>(reinterpret_cast<char*>(At) + offA[i]) = h;
                *reinterpret_cast<uint4*>(reinterpret_cast<char*>(Bt) + offB[i]) = rb[i];
            }
            // issue next tile's loads (hide HBM latency under barrier + MFMA)
            if (e0 + 64 < Edim) {
                #pragma unroll
                for (int i = 0; i < 4; ++i) {
                    ra[i] = *reinterpret_cast<const float4*>(pa[i] + e0 + 64);
                    rb[i] = *reinterpret_cast<const uint4*>(pb[i] + e0 + 64);
                }
            }
            __syncthreads();
            #pragma unroll
            for (int kk = 0; kk < 2; ++kk) {
                int ar = wid * 16 + (lane & 15);
                int abyte = (ar * 128 + kk * 64 + (lane >> 4) * 16) ^ ((ar & 7) << 4);
                bf16x8 af = *reinterpret_cast<const bf16x8*>(reinterpret_cast<char*>(At) + abyte);
                #pragma unroll
                for (int n = 0; n < 8; ++n) {
                    int br = n * 16 + (lane & 15);
                    int bbyte = (br * 128 + kk * 64 + (lane >> 4) * 16) ^ ((br & 7) << 4);
                    bf16x8 bv = *reinterpret_cast<const bf16x8*>(reinterpret_cast<char*>(Bt) + bbyte);
                    acc[n] = __builtin_amdgcn_mfma_f32_16x16x32_bf16(af, bv, acc[n], 0, 0, 0);
                }
            }
            __syncthreads();
        }

        // epilogue: score = v·tanh(acc + qb + conv) + v_b
        float sc[4] = {0.f, 0.f, 0.f, 0.f};
        #pragma unroll
        for (int n = 0; n < 8; ++n) {
            int u = n * 16 + (lane & 15);
            float c0 = s_cw[0][u], c1 = s_cw[1][u], c2 = s_cw[2][u];
            float qbu = s_qb[u], vwu = s_vw[u];
            #pragma unroll
            for (int j = 0; j < 4; ++j) {
                int tl = wid * 16 + (lane >> 4) * 4 + j;
                float conv = s_prev[tl] * c0 + s_prev[tl + 1] * c1 + s_prev[tl + 2] * c2;
                sc[j] += vwu * fast_tanh(acc[n][j] + qbu + conv);
            }
        }
        #pragma unroll
        for (int j = 0; j < 4; ++j) {
            sc[j] += __shfl_xor(sc[j], 1);
            sc[j] += __shfl_xor(sc[j], 2);
            sc[j] += __shfl_xor(sc[j], 4);
            sc[j] += __shfl_xor(sc[j], 8);
        }
        if ((lane & 15) == 0) {
            float vb = v_b[0];
            int tl = wid * 16 + (lane >> 4) * 4;
            #pragma unroll
            for (int j = 0; j < 4; ++j) {
                float s = sc[j] + vb;
                s_score[tl + j] = s;
                attn[b * Tdim + t0 + tl + j] = s;   // raw score; normalized by combine
            }
        }
        __syncthreads();

        // partial softmax over this chunk's 64 rows
        float sv = (t0 + lane < len) ? s_score[lane] : -3.4e38f;
        float m = sv;
        #pragma unroll
        for (int s = 32; s; s >>= 1) m = fmaxf(m, __shfl_xor(m, s));
        float p = (t0 + lane < len) ? __expf(sv - m) : 0.f;
        float l = p;
        #pragma unroll
        for (int s = 32; s; s >>= 1) l += __shfl_xor(l, s);
        if (tid < 64) s_p[tid] = p;
        if (tid == 0) { m_ws[pidx] = m; l_ws[pidx] = l; }
        __syncthreads();

        // partial context: c[e] = sum_t p_t * enc[t,e]  (tile re-read; L2/L3-hot)
        {
            int e4 = (tid & 127) * 4;
            int th = tid >> 7;
            float4 a = make_float4(0.f, 0.f, 0.f, 0.f);
            #pragma unroll 4
            for (int t = th; t < 64; t += 2) {
                float pt = s_p[t];
                float4 v = *reinterpret_cast<const float4*>(encb + (size_t)t * Edim + e4);
                a.x += pt * v.x; a.y += pt * v.y; a.z += pt * v.z; a.w += pt * v.w;
            }
            if (th == 1) *reinterpret_cast<float4*>(&s_cred[(tid & 127) * 4]) = a;
            __syncthreads();
            if (th == 0) {
                float4 o = *reinterpret_cast<const float4*>(&s_cred[tid * 4]);
                a.x += o.x; a.y += o.y; a.z += o.z; a.w += o.w;
                *reinterpret_cast<float4*>(c_ws + (size_t)pidx * Edim + e4) = a;
            }
        }
    } else {
        if (tid == 0) { m_ws[pidx] = -3.4e38f; l_ws[pidx] = 0.f; }
    }

    // ---- last-block-per-b combine (split-K pattern; order-independent) ----
    __threadfence();                                   // release partials device-wide
    if (tid == 0) s_ret = atomicAdd(&cnt[b], 1);
    __syncthreads();
    if (s_ret == NCHUNK - 1) {
        __threadfence();                               // acquire other blocks' partials
        if (wid == 0) {
            float mj = (lane < NCHUNK) ? m_ws[b * NCHUNK + lane] : -3.4e38f;
            float lj = (lane < NCHUNK) ? l_ws[b * NCHUNK + lane] : 0.f;
            float M = mj;
            #pragma unroll
            for (int s = 32; s; s >>= 1) M = fmaxf(M, __shfl_xor(M, s));
            float w = (lj > 0.f) ? __expf(mj - M) : 0.f;
            float L = lj * w;
            #pragma unroll
            for (int s = 32; s; s >>= 1) L += __shfl_xor(L, s);
            if (lane < NCHUNK) s_w[lane] = w;
            if (lane == 0) { sM = M; sinvL = 1.f / L; }
        }
        __syncthreads();
        float M = sM, invL = sinvL;

        // context: each thread owns 2 consecutive e columns
        {
            int e2 = tid * 2;
            float ax = 0.f, ay = 0.f;
            #pragma unroll 4
            for (int j = 0; j < NCHUNK; ++j) {
                float w = s_w[j];
                if (w != 0.f) {
                    float2 v = *reinterpret_cast<const float2*>(c_ws + ((size_t)(b * NCHUNK + j)) * Edim + e2);
                    ax += w * v.x; ay += w * v.y;
                }
            }
            float2 r = make_float2(ax * invL, ay * invL);
            *reinterpret_cast<float2*>(ctx + (size_t)b * Edim + e2) = r;
        }

        // attn: normalize raw scores in place (zero past len)
        #pragma unroll
        for (int i = 0; i < Tdim / 256; ++i) {
            int t = tid + i * 256;
            float s = attn[(size_t)b * Tdim + t];
            attn[(size_t)b * Tdim + t] = (t < len) ? __expf(s - M) * invL : 0.f;
        }
    }
}

extern "C" void kernel_launch(void* const* d_in, const int* in_sizes, int n_in,
                              void* d_out, int out_size, void* d_ws, size_t ws_size,
                              hipStream_t stream) {
    const float* queries = (const float*)d_in[0];
    const float* prev    = (const float*)d_in[1];
    const float* enc     = (const float*)d_in[2];
    const float* conv_w  = (const float*)d_in[3];
    const float* conv_b  = (const float*)d_in[4];
    const float* Wq      = (const float*)d_in[5];
    const float* Wk      = (const float*)d_in[6];
    const float* v_w     = (const float*)d_in[7];
    const float* v_b     = (const float*)d_in[8];
    const float* bparam  = (const float*)d_in[9];
    const int*   lengths = (const int*)d_in[10];

    float* out  = (float*)d_out;
    float* ctx  = out;                       // B*E = 32768
    float* attn = out + Bsz * Edim;          // B*T = 131072 (raw scores -> normalized in place)

    char* ws = (char*)d_ws;
    unsigned short* wkbf = (unsigned short*)ws;                 // 128 KB
    float* qb   = (float*)(ws + 131072);                        // 32 KB
    float* m_ws = (float*)(ws + 163840);                        // 8 KB
    float* l_ws = (float*)(ws + 172032);                        // 8 KB
    int*   cnt  = (int*)  (ws + 180224);                        // 256 B
    float* c_ws = (float*)(ws + 196608);                        // 4 MB

    k_prep<<<2112, 256, 0, stream>>>(queries, Wq, bparam, conv_b, Wk, wkbf, qb, cnt);
    k_score_ctx<<<dim3(NCHUNK, Bsz), 256, 0, stream>>>(enc, prev, wkbf, qb, conv_w, v_w, v_b,
                                                       lengths, attn, m_ws, l_ws, c_ws, ctx, cnt);
}

// Round 4
// 116.855 us; speedup vs baseline: 3.5134x; 3.5134x over previous
//
#include <hip/hip_runtime.h>
#include <hip/hip_bf16.h>

typedef __bf16 bf16x8 __attribute__((ext_vector_type(8)));
typedef float  f32x4  __attribute__((ext_vector_type(4)));

#define Bsz 64
#define Tdim 2048
#define Edim 512
#define Ddim 1024
#define Udim 128
#define NCHUNK 32          // Tdim / 64

__device__ inline unsigned short f2bf(float f) {
    union { float f; unsigned int u; } x{f};
    unsigned int r = x.u + 0x7FFFu + ((x.u >> 16) & 1u);   // RNE
    return (unsigned short)(r >> 16);
}

__device__ inline float fast_tanh(float x) {
    float e = __expf(2.f * x);                 // inf for large x -> 1; 0 for very neg -> -1
    return 1.f - __fdividef(2.f, e + 1.f);
}

// ---- K_prep: multi-role. blocks [0,2048): qb[b,u]; [2048,2112): Wk->bf16 ----
__global__ __launch_bounds__(256) void k_prep(const float* __restrict__ q,
                                              const float* __restrict__ Wq,
                                              const float* __restrict__ bparam,
                                              const float* __restrict__ convb,
                                              const float* __restrict__ Wk,
                                              unsigned short* __restrict__ wkbf,
                                              float* __restrict__ qb) {
    int bid = blockIdx.x, tid = threadIdx.x;
    if (bid >= 2048) {
        int i = ((bid - 2048) * 256 + tid) * 4;
        float4 v = *reinterpret_cast<const float4*>(Wk + i);
        ushort4 h = make_ushort4(f2bf(v.x), f2bf(v.y), f2bf(v.z), f2bf(v.w));
        *reinterpret_cast<ushort4*>(wkbf + i) = h;
        return;
    }
    int gw   = bid * 4 + (tid >> 6);
    int lane = tid & 63;
    int b = gw >> 7, u = gw & 127;
    const float* qr = q  + (size_t)b * Ddim;
    const float* wr = Wq + (size_t)u * Ddim;
    float s = 0.f;
    #pragma unroll
    for (int i = 0; i < 4; ++i) {
        int base = lane * 16 + i * 4;
        float4 a = *reinterpret_cast<const float4*>(qr + base);
        float4 w = *reinterpret_cast<const float4*>(wr + base);
        s += a.x * w.x + a.y * w.y + a.z * w.z + a.w * w.w;
    }
    #pragma unroll
    for (int m = 32; m; m >>= 1) s += __shfl_xor(s, m);
    if (lane == 0) qb[gw] = s + bparam[u] + convb[u];
}

// ---- K1: fused score + partial softmax + partial context (writes partials; NO fences) ----
// 256 thr (4 waves); tile 64 t x 128 u; double-buffered LDS, 1 barrier per K-step
__global__ __launch_bounds__(256) void k_score_ctx(const float* __restrict__ enc,
                                                   const float* __restrict__ prev,
                                                   const unsigned short* __restrict__ wkbf,
                                                   const float* __restrict__ qb,
                                                   const float* __restrict__ conv_w,
                                                   const float* __restrict__ v_w,
                                                   const float* __restrict__ v_b,
                                                   const int* __restrict__ lengths,
                                                   float* __restrict__ score_out,
                                                   float* __restrict__ m_ws,
                                                   float* __restrict__ l_ws,
                                                   float* __restrict__ c_ws) {
    __shared__ alignas(16) unsigned short At[2][64 * 64];   // 16 KB, swizzled, dbuf
    __shared__ alignas(16) unsigned short Bt[2][128 * 64];  // 32 KB, swizzled, dbuf
    __shared__ float s_prev[66];
    __shared__ float s_qb[128];
    __shared__ float s_vw[128];
    __shared__ float s_cw[3][128];
    __shared__ float s_score[64];
    __shared__ float s_p[64];
    __shared__ alignas(16) float s_cred[128 * 4];

    const int tid   = threadIdx.x;
    const int b     = blockIdx.y;
    const int chunk = blockIdx.x;
    const int t0    = chunk * 64;
    const int lane  = tid & 63, wid = tid >> 6;
    const int len   = lengths[b];
    const int pidx  = b * NCHUNK + chunk;

    if (t0 >= len) {                         // fully-masked chunk: empty partial, exit
        if (tid == 0) { m_ws[pidx] = -3.4e38f; l_ws[pidx] = 0.f; }
        return;
    }

    if (tid < 128) {
        s_qb[tid]    = qb[b * 128 + tid];
        s_vw[tid]    = v_w[tid];
        s_cw[0][tid] = conv_w[tid * 3 + 0];
        s_cw[1][tid] = conv_w[tid * 3 + 1];
        s_cw[2][tid] = conv_w[tid * 3 + 2];
    }
    if (tid < 66) {
        int idx = t0 - 1 + tid;
        s_prev[tid] = (idx >= 0 && idx < Tdim) ? prev[b * Tdim + idx] : 0.f;
    }

    const float* encb = enc + ((size_t)b * Tdim + t0) * Edim;

    // hoisted per-thread staging bases
    const float* pa[4]; const unsigned short* pb[4];
    int offA[4], offB[4];
    #pragma unroll
    for (int i = 0; i < 4; ++i) {
        int lin = tid + i * 256;
        int r = lin >> 4, c4 = lin & 15;
        pa[i]   = encb + (size_t)r * Edim + c4 * 4;
        offA[i] = (r * 128 + c4 * 8) ^ ((r & 7) << 4);
        int u = lin >> 3, c8 = lin & 7;
        pb[i]   = wkbf + (size_t)u * Edim + c8 * 8;
        offB[i] = (u * 128 + c8 * 16) ^ ((u & 7) << 4);
    }

    f32x4 acc[8];
    #pragma unroll
    for (int n = 0; n < 8; ++n) acc[n] = (f32x4){0.f, 0.f, 0.f, 0.f};

    float4 ra[4]; uint4 rb[4];
    // tile 0: load -> LDS[0]
    #pragma unroll
    for (int i = 0; i < 4; ++i) {
        ra[i] = *reinterpret_cast<const float4*>(pa[i]);
        rb[i] = *reinterpret_cast<const uint4*>(pb[i]);
    }
    #pragma unroll
    for (int i = 0; i < 4; ++i) {
        ushort4 h = make_ushort4(f2bf(ra[i].x), f2bf(ra[i].y), f2bf(ra[i].z), f2bf(ra[i].w));
        *reinterpret_cast<ushort4*>(reinterpret_cast<char*>(At[0]) + offA[i]) = h;
        *reinterpret_cast<uint4*>(reinterpret_cast<char*>(Bt[0]) + offB[i]) = rb[i];
    }
    // issue tile 1 loads (in flight across barrier)
    #pragma unroll
    for (int i = 0; i < 4; ++i) {
        ra[i] = *reinterpret_cast<const float4*>(pa[i] + 64);
        rb[i] = *reinterpret_cast<const uint4*>(pb[i] + 64);
    }
    __syncthreads();

    #pragma unroll
    for (int it = 0; it < 8; ++it) {
        const int cur = it & 1;
        // MFMA on LDS[cur]
        #pragma unroll
        for (int kk = 0; kk < 2; ++kk) {
            int ar = wid * 16 + (lane & 15);
            int abyte = (ar * 128 + kk * 64 + (lane >> 4) * 16) ^ ((ar & 7) << 4);
            bf16x8 af = *reinterpret_cast<const bf16x8*>(reinterpret_cast<const char*>(At[cur]) + abyte);
            #pragma unroll
            for (int n = 0; n < 8; ++n) {
                int br = n * 16 + (lane & 15);
                int bbyte = (br * 128 + kk * 64 + (lane >> 4) * 16) ^ ((br & 7) << 4);
                bf16x8 bv = *reinterpret_cast<const bf16x8*>(reinterpret_cast<const char*>(Bt[cur]) + bbyte);
                acc[n] = __builtin_amdgcn_mfma_f32_16x16x32_bf16(af, bv, acc[n], 0, 0, 0);
            }
        }
        if (it < 7) {
            // write tile it+1 (regs) -> LDS[cur^1]; disjoint from buffer being read this iter
            #pragma unroll
            for (int i = 0; i < 4; ++i) {
                ushort4 h = make_ushort4(f2bf(ra[i].x), f2bf(ra[i].y), f2bf(ra[i].z), f2bf(ra[i].w));
                *reinterpret_cast<ushort4*>(reinterpret_cast<char*>(At[cur ^ 1]) + offA[i]) = h;
                *reinterpret_cast<uint4*>(reinterpret_cast<char*>(Bt[cur ^ 1]) + offB[i]) = rb[i];
            }
            if (it < 6) {
                const int nb = (it + 2) * 64;
                #pragma unroll
                for (int i = 0; i < 4; ++i) {
                    ra[i] = *reinterpret_cast<const float4*>(pa[i] + nb);
                    rb[i] = *reinterpret_cast<const uint4*>(pb[i] + nb);
                }
            }
            __syncthreads();
        }
    }

    // epilogue: score = v·tanh(acc + qb + conv) + v_b
    float sc[4] = {0.f, 0.f, 0.f, 0.f};
    #pragma unroll
    for (int n = 0; n < 8; ++n) {
        int u = n * 16 + (lane & 15);
        float c0 = s_cw[0][u], c1 = s_cw[1][u], c2 = s_cw[2][u];
        float qbu = s_qb[u], vwu = s_vw[u];
        #pragma unroll
        for (int j = 0; j < 4; ++j) {
            int tl = wid * 16 + (lane >> 4) * 4 + j;
            float conv = s_prev[tl] * c0 + s_prev[tl + 1] * c1 + s_prev[tl + 2] * c2;
            sc[j] += vwu * fast_tanh(acc[n][j] + qbu + conv);
        }
    }
    #pragma unroll
    for (int j = 0; j < 4; ++j) {
        sc[j] += __shfl_xor(sc[j], 1);
        sc[j] += __shfl_xor(sc[j], 2);
        sc[j] += __shfl_xor(sc[j], 4);
        sc[j] += __shfl_xor(sc[j], 8);
    }
    if ((lane & 15) == 0) {
        float vb = v_b[0];
        int tl = wid * 16 + (lane >> 4) * 4;
        #pragma unroll
        for (int j = 0; j < 4; ++j) {
            float s = sc[j] + vb;
            s_score[tl + j] = s;
            score_out[b * Tdim + t0 + tl + j] = s;   // raw score; normalized by combine
        }
    }
    __syncthreads();

    // partial softmax over the chunk's 64 rows
    float sv = (t0 + lane < len) ? s_score[lane] : -3.4e38f;
    float m = sv;
    #pragma unroll
    for (int s = 32; s; s >>= 1) m = fmaxf(m, __shfl_xor(m, s));
    float p = (t0 + lane < len) ? __expf(sv - m) : 0.f;
    float l = p;
    #pragma unroll
    for (int s = 32; s; s >>= 1) l += __shfl_xor(l, s);
    if (tid < 64) s_p[tid] = p;
    if (tid == 0) { m_ws[pidx] = m; l_ws[pidx] = l; }
    __syncthreads();

    // partial context: c[e] = sum_t p_t * enc[t,e]   (tile re-read; L2-hot)
    {
        int e4 = (tid & 127) * 4;
        int th = tid >> 7;
        float4 a = make_float4(0.f, 0.f, 0.f, 0.f);
        #pragma unroll 4
        for (int t = th; t < 64; t += 2) {
            float pt = s_p[t];
            float4 v = *reinterpret_cast<const float4*>(encb + (size_t)t * Edim + e4);
            a.x += pt * v.x; a.y += pt * v.y; a.z += pt * v.z; a.w += pt * v.w;
        }
        if (th == 1) *reinterpret_cast<float4*>(&s_cred[(tid & 127) * 4]) = a;
        __syncthreads();
        if (th == 0) {
            float4 o = *reinterpret_cast<const float4*>(&s_cred[tid * 4]);
            a.x += o.x; a.y += o.y; a.z += o.z; a.w += o.w;
            *reinterpret_cast<float4*>(c_ws + (size_t)pidx * Edim + e4) = a;
        }
    }
}

// ---- K2: combine partials -> context + normalized attn ----
__global__ __launch_bounds__(256) void k_combine(const float* __restrict__ m_ws,
                                                 const float* __restrict__ l_ws,
                                                 const float* __restrict__ c_ws,
                                                 const int* __restrict__ lengths,
                                                 float* __restrict__ ctx,
                                                 float* __restrict__ attn) {
    int b = blockIdx.x, tid = threadIdx.x;
    int lane = tid & 63, wid = tid >> 6;
    __shared__ float s_w[NCHUNK];
    __shared__ float sM, sinvL;

    if (wid == 0) {
        float mj = (lane < NCHUNK) ? m_ws[b * NCHUNK + lane] : -3.4e38f;
        float lj = (lane < NCHUNK) ? l_ws[b * NCHUNK + lane] : 0.f;
        float M = mj;
        #pragma unroll
        for (int s = 32; s; s >>= 1) M = fmaxf(M, __shfl_xor(M, s));
        float w = (lj > 0.f) ? __expf(mj - M) : 0.f;
        float L = lj * w;
        #pragma unroll
        for (int s = 32; s; s >>= 1) L += __shfl_xor(L, s);
        if (lane < NCHUNK) s_w[lane] = w;
        if (lane == 0) { sM = M; sinvL = 1.f / L; }
    }
    __syncthreads();
    float M = sM, invL = sinvL;

    // context: each thread owns 2 consecutive e columns
    {
        int e2 = tid * 2;
        float ax = 0.f, ay = 0.f;
        #pragma unroll 4
        for (int j = 0; j < NCHUNK; ++j) {
            float w = s_w[j];
            if (w != 0.f) {
                float2 v = *reinterpret_cast<const float2*>(c_ws + ((size_t)(b * NCHUNK + j)) * Edim + e2);
                ax += w * v.x; ay += w * v.y;
            }
        }
        float2 r = make_float2(ax * invL, ay * invL);
        *reinterpret_cast<float2*>(ctx + (size_t)b * Edim + e2) = r;
    }

    // attn: normalize raw scores in place (zero past len)
    int len = lengths[b];
    #pragma unroll
    for (int i = 0; i < Tdim / 256; ++i) {
        int t = tid + i * 256;
        float s = attn[(size_t)b * Tdim + t];
        attn[(size_t)b * Tdim + t] = (t < len) ? __expf(s - M) * invL : 0.f;
    }
}

extern "C" void kernel_launch(void* const* d_in, const int* in_sizes, int n_in,
                              void* d_out, int out_size, void* d_ws, size_t ws_size,
                              hipStream_t stream) {
    const float* queries = (const float*)d_in[0];
    const float* prev    = (const float*)d_in[1];
    const float* enc     = (const float*)d_in[2];
    const float* conv_w  = (const float*)d_in[3];
    const float* conv_b  = (const float*)d_in[4];
    const float* Wq      = (const float*)d_in[5];
    const float* Wk      = (const float*)d_in[6];
    const float* v_w     = (const float*)d_in[7];
    const float* v_b     = (const float*)d_in[8];
    const float* bparam  = (const float*)d_in[9];
    const int*   lengths = (const int*)d_in[10];

    float* out  = (float*)d_out;
    float* ctx  = out;                       // B*E = 32768
    float* attn = out + Bsz * Edim;          // B*T = 131072 (raw scores -> normalized in place)

    char* ws = (char*)d_ws;
    unsigned short* wkbf = (unsigned short*)ws;                 // 128 KB
    float* qb   = (float*)(ws + 131072);                        // 32 KB
    float* m_ws = (float*)(ws + 163840);                        // 8 KB
    float* l_ws = (float*)(ws + 172032);                        // 8 KB
    float* c_ws = (float*)(ws + 196608);                        // 4 MB

    k_prep<<<2112, 256, 0, stream>>>(queries, Wq, bparam, conv_b, Wk, wkbf, qb);
    k_score_ctx<<<dim3(NCHUNK, Bsz), 256, 0, stream>>>(enc, prev, wkbf, qb, conv_w, v_w, v_b,
                                                       lengths, attn, m_ws, l_ws, c_ws);
    k_combine<<<Bsz, 256, 0, stream>>>(m_ws, l_ws, c_ws, lengths, ctx, attn);
}

// Round 5
// 80.348 us; speedup vs baseline: 5.1098x; 1.4544x over previous
//
#include <hip/hip_runtime.h>
#include <hip/hip_bf16.h>

typedef __bf16 bf16x8 __attribute__((ext_vector_type(8)));
typedef float  f32x4  __attribute__((ext_vector_type(4)));

#define Bsz 64
#define Tdim 2048
#define Edim 512
#define Ddim 1024
#define Udim 128
#define CHUNK 128
#define NCHUNK 16          // Tdim / CHUNK

__device__ inline unsigned short f2bf(float f) {
    union { float f; unsigned int u; } x{f};
    unsigned int r = x.u + 0x7FFFu + ((x.u >> 16) & 1u);   // RNE
    return (unsigned short)(r >> 16);
}

__device__ inline float fast_tanh(float x) {
    float e = __expf(2.f * x);                 // inf for large x -> 1; 0 for very neg -> -1
    return 1.f - __fdividef(2.f, e + 1.f);
}

// ---- K_prep: blocks [0,512): qb (4 jobs/wave); [512,528): Wk->bf16 (4 iters) ----
__global__ __launch_bounds__(256) void k_prep(const float* __restrict__ q,
                                              const float* __restrict__ Wq,
                                              const float* __restrict__ bparam,
                                              const float* __restrict__ convb,
                                              const float* __restrict__ Wk,
                                              unsigned short* __restrict__ wkbf,
                                              float* __restrict__ qb) {
    int bid = blockIdx.x, tid = threadIdx.x;
    if (bid >= 512) {
        int cb = bid - 512;
        #pragma unroll
        for (int k = 0; k < 4; ++k) {
            int i = (((cb * 4 + k) * 256) + tid) * 4;
            float4 v = *reinterpret_cast<const float4*>(Wk + i);
            ushort4 h = make_ushort4(f2bf(v.x), f2bf(v.y), f2bf(v.z), f2bf(v.w));
            *reinterpret_cast<ushort4*>(wkbf + i) = h;
        }
        return;
    }
    int wg   = bid * 4 + (tid >> 6);          // [0,2048)
    int lane = tid & 63;
    int b  = wg >> 5;                          // 32 waves per b
    int u0 = (wg & 31) * 4;                    // 4 consecutive u per wave
    const float* qr = q + (size_t)b * Ddim + lane * 16;
    float4 qv[4];
    #pragma unroll
    for (int i = 0; i < 4; ++i) qv[i] = *reinterpret_cast<const float4*>(qr + i * 4);
    float s[4];
    #pragma unroll
    for (int jj = 0; jj < 4; ++jj) {
        const float* wr = Wq + (size_t)(u0 + jj) * Ddim + lane * 16;
        float acc = 0.f;
        #pragma unroll
        for (int i = 0; i < 4; ++i) {
            float4 w = *reinterpret_cast<const float4*>(wr + i * 4);
            acc += qv[i].x * w.x + qv[i].y * w.y + qv[i].z * w.z + qv[i].w * w.w;
        }
        s[jj] = acc;
    }
    #pragma unroll
    for (int m = 32; m; m >>= 1) {
        #pragma unroll
        for (int jj = 0; jj < 4; ++jj) s[jj] += __shfl_xor(s[jj], m);
    }
    if (lane == 0) {
        #pragma unroll
        for (int jj = 0; jj < 4; ++jj)
            qb[b * 128 + u0 + jj] = s[jj] + bparam[u0 + jj] + convb[u0 + jj];
    }
}

// ---- K1: fused score + partial softmax + partial context; chunk=128 rows ----
// 256 thr (4 waves); tile 128 t x 128 u; single-buffered LDS, K-steps of 64 over E
__global__ __launch_bounds__(256) void k_score_ctx(const float* __restrict__ enc,
                                                   const float* __restrict__ prev,
                                                   const unsigned short* __restrict__ wkbf,
                                                   const float* __restrict__ qb,
                                                   const float* __restrict__ conv_w,
                                                   const float* __restrict__ v_w,
                                                   const float* __restrict__ v_b,
                                                   const int* __restrict__ lengths,
                                                   float* __restrict__ score_out,
                                                   float* __restrict__ m_ws,
                                                   float* __restrict__ l_ws,
                                                   float* __restrict__ c_ws) {
    __shared__ alignas(16) unsigned short At[128 * 64];     // 16 KB, swizzled
    __shared__ alignas(16) unsigned short Bt[128 * 64];     // 16 KB, swizzled
    __shared__ float s_prev[130];
    __shared__ float s_qb[128];
    __shared__ float s_vw[128];
    __shared__ float s_cw[3][128];
    __shared__ float s_score[128];
    __shared__ float s_p[128];
    __shared__ alignas(16) float s_cred[128 * 4];

    const int tid   = threadIdx.x;
    const int b     = blockIdx.y;
    const int chunk = blockIdx.x;
    const int t0    = chunk * CHUNK;
    const int lane  = tid & 63, wid = tid >> 6;
    const int len   = lengths[b];
    const int pidx  = b * NCHUNK + chunk;

    if (t0 >= len) {                         // fully-masked chunk: empty partial, exit
        if (tid == 0) { m_ws[pidx] = -3.4e38f; l_ws[pidx] = 0.f; }
        return;
    }

    if (tid < 128) {
        s_qb[tid]    = qb[b * 128 + tid];
        s_vw[tid]    = v_w[tid];
        s_cw[0][tid] = conv_w[tid * 3 + 0];
        s_cw[1][tid] = conv_w[tid * 3 + 1];
        s_cw[2][tid] = conv_w[tid * 3 + 2];
    }
    if (tid < 130) {
        int idx = t0 - 1 + tid;
        s_prev[tid] = (idx >= 0 && idx < Tdim) ? prev[b * Tdim + idx] : 0.f;
    }

    const float* encb = enc + ((size_t)b * Tdim + t0) * Edim;

    f32x4 acc[2][8];
    #pragma unroll
    for (int m2 = 0; m2 < 2; ++m2)
        #pragma unroll
        for (int n = 0; n < 8; ++n) acc[m2][n] = (f32x4){0.f, 0.f, 0.f, 0.f};

    for (int e0 = 0; e0 < Edim; e0 += 64) {
        // stage A: enc[t0..t0+127][e0..e0+63] -> bf16, XOR-swizzled 128B rows
        #pragma unroll
        for (int i = 0; i < 8; ++i) {
            int lin = tid + i * 256;
            int r = lin >> 4, c4 = lin & 15;
            float4 v = *reinterpret_cast<const float4*>(encb + (size_t)r * Edim + e0 + c4 * 4);
            ushort4 h = make_ushort4(f2bf(v.x), f2bf(v.y), f2bf(v.z), f2bf(v.w));
            int off = (r * 128 + c4 * 8) ^ ((r & 7) << 4);
            *reinterpret_cast<ushort4*>(reinterpret_cast<char*>(At) + off) = h;
        }
        // stage B: Wk_bf16[0..127][e0..e0+63]
        #pragma unroll
        for (int i = 0; i < 4; ++i) {
            int lin = tid + i * 256;
            int u = lin >> 3, c8 = lin & 7;
            uint4 w = *reinterpret_cast<const uint4*>(wkbf + (size_t)u * Edim + e0 + c8 * 8);
            int off = (u * 128 + c8 * 16) ^ ((u & 7) << 4);
            *reinterpret_cast<uint4*>(reinterpret_cast<char*>(Bt) + off) = w;
        }
        __syncthreads();
        #pragma unroll
        for (int kk = 0; kk < 2; ++kk) {
            #pragma unroll
            for (int m2 = 0; m2 < 2; ++m2) {
                int ar = wid * 32 + m2 * 16 + (lane & 15);
                int abyte = (ar * 128 + kk * 64 + (lane >> 4) * 16) ^ ((ar & 7) << 4);
                bf16x8 af = *reinterpret_cast<const bf16x8*>(reinterpret_cast<const char*>(At) + abyte);
                #pragma unroll
                for (int n = 0; n < 8; ++n) {
                    int br = n * 16 + (lane & 15);
                    int bbyte = (br * 128 + kk * 64 + (lane >> 4) * 16) ^ ((br & 7) << 4);
                    bf16x8 bv = *reinterpret_cast<const bf16x8*>(reinterpret_cast<const char*>(Bt) + bbyte);
                    acc[m2][n] = __builtin_amdgcn_mfma_f32_16x16x32_bf16(af, bv, acc[m2][n], 0, 0, 0);
                }
            }
        }
        __syncthreads();
    }

    // epilogue: score = v·tanh(acc + qb + conv) + v_b
    float sc[2][4] = {{0.f,0.f,0.f,0.f},{0.f,0.f,0.f,0.f}};
    #pragma unroll
    for (int m2 = 0; m2 < 2; ++m2) {
        #pragma unroll
        for (int n = 0; n < 8; ++n) {
            int u = n * 16 + (lane & 15);
            float c0 = s_cw[0][u], c1 = s_cw[1][u], c2 = s_cw[2][u];
            float qbu = s_qb[u], vwu = s_vw[u];
            #pragma unroll
            for (int j = 0; j < 4; ++j) {
                int tl = wid * 32 + m2 * 16 + (lane >> 4) * 4 + j;
                float conv = s_prev[tl] * c0 + s_prev[tl + 1] * c1 + s_prev[tl + 2] * c2;
                sc[m2][j] += vwu * fast_tanh(acc[m2][n][j] + qbu + conv);
            }
        }
    }
    #pragma unroll
    for (int m2 = 0; m2 < 2; ++m2)
        #pragma unroll
        for (int j = 0; j < 4; ++j) {
            sc[m2][j] += __shfl_xor(sc[m2][j], 1);
            sc[m2][j] += __shfl_xor(sc[m2][j], 2);
            sc[m2][j] += __shfl_xor(sc[m2][j], 4);
            sc[m2][j] += __shfl_xor(sc[m2][j], 8);
        }
    if ((lane & 15) == 0) {
        float vb = v_b[0];
        #pragma unroll
        for (int m2 = 0; m2 < 2; ++m2) {
            int tl = wid * 32 + m2 * 16 + (lane >> 4) * 4;
            #pragma unroll
            for (int j = 0; j < 4; ++j) {
                float s = sc[m2][j] + vb;
                s_score[tl + j] = s;
                score_out[b * Tdim + t0 + tl + j] = s;   // raw; normalized by combine
            }
        }
    }
    __syncthreads();

    // partial softmax over the chunk's 128 rows (lane covers rows lane, lane+64)
    float sv0 = (t0 + lane < len)      ? s_score[lane]      : -3.4e38f;
    float sv1 = (t0 + 64 + lane < len) ? s_score[lane + 64] : -3.4e38f;
    float m = fmaxf(sv0, sv1);
    #pragma unroll
    for (int s = 32; s; s >>= 1) m = fmaxf(m, __shfl_xor(m, s));
    float p0 = (t0 + lane < len)      ? __expf(sv0 - m) : 0.f;
    float p1 = (t0 + 64 + lane < len) ? __expf(sv1 - m) : 0.f;
    float l = p0 + p1;
    #pragma unroll
    for (int s = 32; s; s >>= 1) l += __shfl_xor(l, s);
    if (tid < 64) { s_p[tid] = p0; s_p[tid + 64] = p1; }
    if (tid == 0) { m_ws[pidx] = m; l_ws[pidx] = l; }
    __syncthreads();

    // partial context: c[e] = sum_t p_t * enc[t,e]   (tile re-read; L2/L3-hot)
    {
        int e4 = (tid & 127) * 4;
        int th = tid >> 7;
        float4 a = make_float4(0.f, 0.f, 0.f, 0.f);
        #pragma unroll 4
        for (int t = th; t < CHUNK; t += 2) {
            float pt = s_p[t];
            float4 v = *reinterpret_cast<const float4*>(encb + (size_t)t * Edim + e4);
            a.x += pt * v.x; a.y += pt * v.y; a.z += pt * v.z; a.w += pt * v.w;
        }
        if (th == 1) *reinterpret_cast<float4*>(&s_cred[(tid & 127) * 4]) = a;
        __syncthreads();
        if (th == 0) {
            float4 o = *reinterpret_cast<const float4*>(&s_cred[tid * 4]);
            a.x += o.x; a.y += o.y; a.z += o.z; a.w += o.w;
            *reinterpret_cast<float4*>(c_ws + (size_t)pidx * Edim + e4) = a;
        }
    }
}

// ---- K2: combine partials -> context + normalized attn ----
__global__ __launch_bounds__(256) void k_combine(const float* __restrict__ m_ws,
                                                 const float* __restrict__ l_ws,
                                                 const float* __restrict__ c_ws,
                                                 const int* __restrict__ lengths,
                                                 float* __restrict__ ctx,
                                                 float* __restrict__ attn) {
    int b = blockIdx.x, tid = threadIdx.x;
    int lane = tid & 63, wid = tid >> 6;
    __shared__ float s_w[NCHUNK];
    __shared__ float sM, sinvL;

    if (wid == 0) {
        float mj = (lane < NCHUNK) ? m_ws[b * NCHUNK + lane] : -3.4e38f;
        float lj = (lane < NCHUNK) ? l_ws[b * NCHUNK + lane] : 0.f;
        float M = mj;
        #pragma unroll
        for (int s = 32; s; s >>= 1) M = fmaxf(M, __shfl_xor(M, s));
        float w = (lj > 0.f) ? __expf(mj - M) : 0.f;
        float L = lj * w;
        #pragma unroll
        for (int s = 32; s; s >>= 1) L += __shfl_xor(L, s);
        if (lane < NCHUNK) s_w[lane] = w;
        if (lane == 0) { sM = M; sinvL = 1.f / L; }
    }
    __syncthreads();
    float M = sM, invL = sinvL;

    // context: each thread owns 2 consecutive e columns
    {
        int e2 = tid * 2;
        float ax = 0.f, ay = 0.f;
        #pragma unroll 4
        for (int j = 0; j < NCHUNK; ++j) {
            float w = s_w[j];
            if (w != 0.f) {
                float2 v = *reinterpret_cast<const float2*>(c_ws + ((size_t)(b * NCHUNK + j)) * Edim + e2);
                ax += w * v.x; ay += w * v.y;
            }
        }
        float2 r = make_float2(ax * invL, ay * invL);
        *reinterpret_cast<float2*>(ctx + (size_t)b * Edim + e2) = r;
    }

    // attn: normalize raw scores in place (zero past len)
    int len = lengths[b];
    #pragma unroll
    for (int i = 0; i < Tdim / 256; ++i) {
        int t = tid + i * 256;
        float s = attn[(size_t)b * Tdim + t];
        attn[(size_t)b * Tdim + t] = (t < len) ? __expf(s - M) * invL : 0.f;
    }
}

extern "C" void kernel_launch(void* const* d_in, const int* in_sizes, int n_in,
                              void* d_out, int out_size, void* d_ws, size_t ws_size,
                              hipStream_t stream) {
    const float* queries = (const float*)d_in[0];
    const float* prev    = (const float*)d_in[1];
    const float* enc     = (const float*)d_in[2];
    const float* conv_w  = (const float*)d_in[3];
    const float* conv_b  = (const float*)d_in[4];
    const float* Wq      = (const float*)d_in[5];
    const float* Wk      = (const float*)d_in[6];
    const float* v_w     = (const float*)d_in[7];
    const float* v_b     = (const float*)d_in[8];
    const float* bparam  = (const float*)d_in[9];
    const int*   lengths = (const int*)d_in[10];

    float* out  = (float*)d_out;
    float* ctx  = out;                       // B*E = 32768
    float* attn = out + Bsz * Edim;          // B*T = 131072 (raw scores -> normalized in place)

    char* ws = (char*)d_ws;
    unsigned short* wkbf = (unsigned short*)ws;                 // 128 KB
    float* qb   = (float*)(ws + 131072);                        // 32 KB
    float* m_ws = (float*)(ws + 163840);                        // 4 KB
    float* l_ws = (float*)(ws + 172032);                        // 4 KB
    float* c_ws = (float*)(ws + 196608);                        // 2 MB

    k_prep<<<528, 256, 0, stream>>>(queries, Wq, bparam, conv_b, Wk, wkbf, qb);
    k_score_ctx<<<dim3(NCHUNK, Bsz), 256, 0, stream>>>(enc, prev, wkbf, qb, conv_w, v_w, v_b,
                                                       lengths, attn, m_ws, l_ws, c_ws);
    k_combine<<<Bsz, 256, 0, stream>>>(m_ws, l_ws, c_ws, lengths, ctx, attn);
}